// Round 2
// baseline (1166.750 us; speedup 1.0000x reference)
//
#include <hip/hip_runtime.h>
#include <hip/hip_bf16.h>

typedef unsigned long long u64;
typedef unsigned int u32;

#define NB   64
#define NPOS 1024
#define NOUT 25
#define NCLS 20
#define WROW 26            // padded f64 weights per channel

// ---- workspace layout (bytes) ----
#define OFF_W64   0          // double wpad[512*26] = 106496
#define OFF_B64   106496     // double b64[25]      = 200
#define OFF_ORDER 106752     // int   order[64*1024]        = 262144
#define OFF_SBOX  368896     // float4 sbox[64*1024]        = 1048576
#define OFF_SCLS  1417472    // int   scls[64*1024]         = 262144
#define OFF_VALID 1679616    // u64   validW[64*16]         = 8192
#define OFF_MASK  1687808    // u64   masks[64*1024*16]     = 8388608 -> end 10076416

// ---------------- kernel 0: weights -> f64, layout [c][26] (pad 0) -----------
__global__ __launch_bounds__(256) void k_cvt(const float* __restrict__ w,
                                             const float* __restrict__ bias,
                                             double* __restrict__ wpad,
                                             double* __restrict__ b64)
{
    int idx = blockIdx.x * 256 + threadIdx.x;
    if (idx < 512 * WROW) {
        int c = idx / WROW, o = idx - c * WROW;
        wpad[idx] = (o < NOUT) ? (double)w[o * 512 + c] : 0.0;
    }
    if (idx < NOUT) b64[idx] = (double)bias[idx];
}

// ---------------- kernel 1: f64 GEMM (LDS weights, split-K) + epilogue -------
// block = 512 thr = 32 quads x 16 k-slices; each thread: 4 positions x 32 ch
__global__ __launch_bounds__(512, 2) void k_main(const float* __restrict__ feat,
                                                 const double* __restrict__ wpad_g,
                                                 const double* __restrict__ b64,
                                                 float* __restrict__ boxes_out,
                                                 float* __restrict__ scores_out,
                                                 float* __restrict__ cls_out)
{
    __shared__ __align__(16) double ldsw[512 * WROW];   // 106496 B, reused for reduce
    const int b   = blockIdx.y;
    const int tid = threadIdx.x;

    // stage weights (f64) into LDS
    {
        const double2* src = (const double2*)wpad_g;
        double2* dst = (double2*)ldsw;
        for (int i = tid; i < 512 * WROW / 2; i += 512) dst[i] = src[i];
    }
    __syncthreads();

    const int q  = tid & 31;        // quad (4 positions)
    const int s  = tid >> 5;        // k-slice 0..15
    const int c0 = s * 32;
    const int n0 = blockIdx.x * 128 + q * 4;
    const float4* f4 = ((const float4*)(feat + (size_t)b * 512 * NPOS)) + (n0 >> 2);

    double acc[4][25];
#pragma unroll
    for (int pp = 0; pp < 4; ++pp)
#pragma unroll
        for (int o = 0; o < NOUT; ++o) acc[pp][o] = 0.0;

#define PROC(V, CH) do {                                                     \
    const double2* __restrict__ wr = (const double2*)(ldsw + (CH) * WROW);   \
    double d0 = (double)(V).x, d1 = (double)(V).y,                           \
           d2 = (double)(V).z, d3 = (double)(V).w;                           \
    _Pragma("unroll")                                                        \
    for (int qq = 0; qq < 12; ++qq) {                                        \
        double2 w2 = wr[qq];                                                 \
        acc[0][2*qq]   = fma(d0, w2.x, acc[0][2*qq]);                        \
        acc[0][2*qq+1] = fma(d0, w2.y, acc[0][2*qq+1]);                      \
        acc[1][2*qq]   = fma(d1, w2.x, acc[1][2*qq]);                        \
        acc[1][2*qq+1] = fma(d1, w2.y, acc[1][2*qq+1]);                      \
        acc[2][2*qq]   = fma(d2, w2.x, acc[2][2*qq]);                        \
        acc[2][2*qq+1] = fma(d2, w2.y, acc[2][2*qq+1]);                      \
        acc[3][2*qq]   = fma(d3, w2.x, acc[3][2*qq]);                        \
        acc[3][2*qq+1] = fma(d3, w2.y, acc[3][2*qq+1]);                      \
    }                                                                        \
    { double w24 = ldsw[(CH) * WROW + 24];                                   \
      acc[0][24] = fma(d0, w24, acc[0][24]);                                 \
      acc[1][24] = fma(d1, w24, acc[1][24]);                                 \
      acc[2][24] = fma(d2, w24, acc[2][24]);                                 \
      acc[3][24] = fma(d3, w24, acc[3][24]); }                               \
} while (0)

    // channel loop, manual 2x unroll, depth-2 prefetch
    float4 va = f4[(size_t)(c0 + 0) << 8];
    float4 vb = f4[(size_t)(c0 + 1) << 8];
#pragma unroll 1
    for (int t = 0; t < 32; t += 2) {
        int t2 = (t + 2 < 32) ? (t + 2) : 0;
        int t3 = (t + 3 < 32) ? (t + 3) : 0;
        float4 vc = f4[(size_t)(c0 + t2) << 8];
        float4 vd = f4[(size_t)(c0 + t3) << 8];
        PROC(va, c0 + t);
        PROC(vb, c0 + t + 1);
        va = vc; vb = vd;
    }
#undef PROC

    // -------- deterministic tree reduction 16 -> 1 (reuse weight LDS) -------
    __syncthreads();
    double* red = ldsw;
#define WR(IDX) do { double* dstb = red + (size_t)(IDX) * 101;               \
    _Pragma("unroll") for (int pp = 0; pp < 4; ++pp)                         \
    _Pragma("unroll") for (int o = 0; o < 25; ++o)                           \
        dstb[pp * 25 + o] = acc[pp][o]; } while (0)
#define RD(IDX) do { const double* srcb = red + (size_t)(IDX) * 101;         \
    _Pragma("unroll") for (int pp = 0; pp < 4; ++pp)                         \
    _Pragma("unroll") for (int o = 0; o < 25; ++o)                           \
        acc[pp][o] += srcb[pp * 25 + o]; } while (0)

    // round 1 (16->8) in two quad-halves (LDS capacity)
    {
        int ql = q & 15;
#pragma unroll 1
        for (int h = 0; h < 2; ++h) {
            bool mine = ((q >> 4) == h);
            if (mine && s >= 8) WR((s - 8) * 16 + ql);
            __syncthreads();
            if (mine && s < 8)  RD(s * 16 + ql);
            __syncthreads();
        }
    }
    // round 2 (8->4)
    if (s >= 4 && s < 8) WR((s - 4) * 32 + q);
    __syncthreads();
    if (s < 4) RD(s * 32 + q);
    __syncthreads();
    // round 3 (4->2)
    if (s == 2 || s == 3) WR((s - 2) * 32 + q);
    __syncthreads();
    if (s < 2) RD(s * 32 + q);
    __syncthreads();
    // round 4 (2->1)
    if (s == 1) WR(q);
    __syncthreads();

    if (s == 0) {
        RD(q);
#pragma unroll 1
        for (int pp = 0; pp < 4; ++pp) {
            double p[25];
#pragma unroll
            for (int o = 0; o < NOUT; ++o) p[o] = acc[pp][o] + b64[o];

            double conf = 1.0 / (1.0 + exp(-p[0]));
            double m = p[1];
#pragma unroll
            for (int i = 2; i <= NCLS; ++i) m = fmax(m, p[i]);
            double e[NCLS];
            double ssum = 0.0;
#pragma unroll
            for (int i = 0; i < NCLS; ++i) { e[i] = exp(p[1 + i] - m); ssum += e[i]; }
            double best = -1.0; int ci = 0;
#pragma unroll
            for (int i = 0; i < NCLS; ++i) {
                double si = conf * (e[i] / ssum);
                if (si > best) { best = si; ci = i; }
            }

            int n = n0 + pp;
            int gx = n & 31, gy = n >> 5;
            double sx = 1.0 / (1.0 + exp(-p[21]));
            double sy = 1.0 / (1.0 + exp(-p[22]));
            double cx = (sx + (double)gx) * 32.0;
            double cy = (sy + (double)gy) * 32.0;
            double bw = exp(p[23]), bh = exp(p[24]);
            double x1 = (cx - bw * 0.5) * (1.0 / 1024.0);
            double y1 = (cy - bh * 0.5) * (1.0 / 1024.0);
            double x2 = (cx + bw * 0.5) * (1.0 / 1024.0);
            double y2 = (cy + bh * 0.5) * (1.0 / 1024.0);
            x1 = fmin(fmax(x1, 0.0), 1.0); y1 = fmin(fmax(y1, 0.0), 1.0);
            x2 = fmin(fmax(x2, 0.0), 1.0); y2 = fmin(fmax(y2, 0.0), 1.0);

            int gi = b * NPOS + n;
            ((float4*)boxes_out)[gi] = make_float4((float)x1, (float)y1, (float)x2, (float)y2);
            scores_out[gi] = (float)best;
            cls_out[gi]    = (float)ci;
        }
    }
#undef WR
#undef RD
}

// ---------------- kernel 2: per-batch bitonic sort (desc score, stable) -------
__global__ __launch_bounds__(256) void k_sort(const float* __restrict__ scores,
                                              const float* __restrict__ boxes,
                                              const float* __restrict__ cls,
                                              int* __restrict__ order,
                                              float4* __restrict__ sbox,
                                              int* __restrict__ scls,
                                              u64* __restrict__ validW)
{
    __shared__ u64 key[NPOS];
    __shared__ u64 vw[16];
    int b = blockIdx.x, tid = threadIdx.x;

    for (int ppos = tid; ppos < NPOS; ppos += 256) {
        u32 bits = __float_as_uint(scores[b * NPOS + ppos]);
        u32 d = ~(bits | 0x80000000u);   // descending-monotone key (scores >= 0)
        key[ppos] = ((u64)d << 32) | (u32)ppos;
    }
    if (tid < 16) vw[tid] = 0ull;
    __syncthreads();

    for (int k = 2; k <= NPOS; k <<= 1) {
        for (int j = k >> 1; j > 0; j >>= 1) {
            for (int idx = tid; idx < NPOS; idx += 256) {
                int l = idx ^ j;
                if (l > idx) {
                    u64 a = key[idx], c = key[l];
                    bool up = ((idx & k) == 0);
                    if ((a > c) == up) { key[idx] = c; key[l] = a; }
                }
            }
            __syncthreads();
        }
    }

    for (int ppos = tid; ppos < NPOS; ppos += 256) {
        u64 kk = key[ppos];
        int idx = (int)(kk & 0xffffffffu);
        order[b * NPOS + ppos] = idx;
        sbox [b * NPOS + ppos] = ((const float4*)boxes)[b * NPOS + idx];
        scls [b * NPOS + ppos] = (int)cls[b * NPOS + idx];
        u32 sb = (~(u32)(kk >> 32)) & 0x7fffffffu;
        float sc = __uint_as_float(sb);
        if (sc > 0.01f) atomicOr(&vw[ppos >> 6], 1ull << (ppos & 63));
    }
    __syncthreads();
    if (tid < 16) validW[b * 16 + tid] = vw[tid];
}

// ---------------- kernel 3: suppression bitmask build (upper triangle) --------
__global__ __launch_bounds__(256) void k_mask(const float4* __restrict__ sbox,
                                              const int* __restrict__ scls,
                                              u64* __restrict__ masks)
{
    __shared__ float4 boxl[NPOS];
    __shared__ float  arl[NPOS];
    __shared__ int    cll[NPOS];
    int b = blockIdx.y, rb = blockIdx.x, tid = threadIdx.x;

    for (int ppos = tid; ppos < NPOS; ppos += 256) {
        float4 bb = sbox[b * NPOS + ppos];
        boxl[ppos] = bb;
        arl[ppos] = (bb.z - bb.x) * (bb.w - bb.y);
        cll[ppos] = scls[b * NPOS + ppos];
    }
    __syncthreads();

    int i = rb * 64 + (tid >> 2);
    int wbase = tid & 3;
    float4 bi = boxl[i];
    float ai = arl[i];
    int ci_ = cll[i];
    u64* mrow = masks + ((size_t)(b * NPOS + i) << 4);

#pragma unroll
    for (int s = 0; s < 4; ++s) {
        int w = wbase + 4 * s;
        u64 bits = 0ull;
        if (w >= rb) {
            for (int t = 0; t < 64; ++t) {
                int jj = (t + 2 * wbase) & 63;
                int j = w * 64 + jj;
                float4 bj = boxl[j];
                float xx1 = fmaxf(bi.x, bj.x), yy1 = fmaxf(bi.y, bj.y);
                float xx2 = fminf(bi.z, bj.z), yy2 = fminf(bi.w, bj.w);
                float ww = fmaxf(1e-28f, xx2 - xx1);
                float hh = fmaxf(1e-28f, yy2 - yy1);
                float inter = ww * hh;
                float uni = ai + arl[j] - inter;
                bool sup = (cll[j] == ci_) && (uni > 0.0f) &&
                           (inter > 0.5f * uni) && (j > i);
                bits |= ((u64)sup) << jj;
            }
        }
        mrow[w] = bits;
    }
}

// ---------------- kernel 4: sequential suppression scan + scatter keep --------
__global__ __launch_bounds__(64) void k_scan(const u64* __restrict__ validW,
                                             const u64* __restrict__ masks,
                                             const int* __restrict__ order,
                                             float* __restrict__ keep_out)
{
    int b = blockIdx.x, lane = threadIdx.x;
    u64 keep = (lane < 16) ? validW[b * 16 + lane] : 0ull;
    const u64* M = masks + (size_t)b * NPOS * 16;
    int myrow = lane >> 4;
    int myw = lane & 15;

    u64 buf[8];
#pragma unroll
    for (int d = 0; d < 8; ++d)
        buf[d] = M[(d * 4 + myrow) * 16 + myw];

    for (int g0 = 0; g0 < 256; g0 += 8) {
#pragma unroll
        for (int d = 0; d < 8; ++d) {
            int g = g0 + d;
            u64 cur = buf[d];
            int gp = g + 8;
            buf[d] = (gp < 256) ? M[(gp * 4 + myrow) * 16 + myw] : 0ull;
            if (__any(cur != 0ull)) {
#pragma unroll
                for (int r = 0; r < 4; ++r) {
                    int i = g * 4 + r;
                    u64 kw = __shfl(keep, i >> 6);
                    if ((kw >> (i & 63)) & 1ull) {
                        u64 mm = __shfl(cur, r * 16 + myw);
                        if (lane < 16) keep &= ~mm;
                    }
                }
            }
        }
    }

#pragma unroll
    for (int t = 0; t < 16; ++t) {
        int ppos = t * 64 + lane;
        u64 kw = __shfl(keep, t);
        float v = ((kw >> lane) & 1ull) ? 1.0f : 0.0f;
        keep_out[b * NPOS + order[b * NPOS + ppos]] = v;
    }
}

// ------------------------------------------------------------------------------
extern "C" void kernel_launch(void* const* d_in, const int* in_sizes, int n_in,
                              void* d_out, int out_size, void* d_ws, size_t ws_size,
                              hipStream_t stream)
{
    const float* feat = (const float*)d_in[0];
    const float* w    = (const float*)d_in[1];
    const float* bias = (const float*)d_in[2];

    float* out = (float*)d_out;
    float* boxes_out  = out;
    float* scores_out = out + NB * NPOS * 4;
    float* cls_out    = out + NB * NPOS * 5;
    float* keep_out   = out + NB * NPOS * 6;

    char* ws = (char*)d_ws;
    double* wpad  = (double*)(ws + OFF_W64);
    double* b64   = (double*)(ws + OFF_B64);
    int*    order = (int*)   (ws + OFF_ORDER);
    float4* sbox  = (float4*)(ws + OFF_SBOX);
    int*    scls  = (int*)   (ws + OFF_SCLS);
    u64*    validW= (u64*)   (ws + OFF_VALID);
    u64*    masks = (u64*)   (ws + OFF_MASK);

    hipLaunchKernelGGL(k_cvt,  dim3(52),     dim3(256), 0, stream, w, bias, wpad, b64);
    hipLaunchKernelGGL(k_main, dim3(8, 64),  dim3(512), 0, stream, feat, wpad, b64,
                       boxes_out, scores_out, cls_out);
    hipLaunchKernelGGL(k_sort, dim3(64),     dim3(256), 0, stream, scores_out,
                       boxes_out, cls_out, order, sbox, scls, validW);
    hipLaunchKernelGGL(k_mask, dim3(16, 64), dim3(256), 0, stream, sbox, scls, masks);
    hipLaunchKernelGGL(k_scan, dim3(64),     dim3(64),  0, stream, validW, masks,
                       order, keep_out);
}

// Round 3
// 198.909 us; speedup vs baseline: 5.8658x; 5.8658x over previous
//
#include <hip/hip_runtime.h>
#include <hip/hip_bf16.h>

typedef unsigned long long u64;
typedef unsigned int u32;

#define NB   64
#define NPOS 1024
#define NOUT 25
#define NCLS 20
#define WROW 26            // padded f64 weights per channel (16B-aligned rows)

// ---- workspace layout (bytes) ----
#define OFF_W64   0          // double wpad[512*26] = 106496
#define OFF_B64   106496     // double b64[25]      = 200
#define OFF_ORDER 106752     // int   order[64*1024]        = 262144
#define OFF_SBOX  368896     // float4 sbox[64*1024]        = 1048576
#define OFF_SCLS  1417472    // int   scls[64*1024]         = 262144
#define OFF_VALID 1679616    // u64   validW[64*16]         = 8192
#define OFF_MASK  1687808    // u64   masks[64*1024*16]     = 8388608 -> end 10076416

// ---------------- kernel 0: weights -> f64, layout [c][26] (pad 0) -----------
__global__ __launch_bounds__(256) void k_cvt(const float* __restrict__ w,
                                             const float* __restrict__ bias,
                                             double* __restrict__ wpad,
                                             double* __restrict__ b64)
{
    int idx = blockIdx.x * 256 + threadIdx.x;
    if (idx < 512 * WROW) {
        int c = idx / WROW, o = idx - c * WROW;
        wpad[idx] = (o < NOUT) ? (double)w[o * 512 + c] : 0.0;
    }
    if (idx < NOUT) b64[idx] = (double)bias[idx];
}

// ---------------- kernel 1: f64 GEMV (LDS-broadcast weights) + epilogue ------
// 1 position per thread; 256 thr/block; grid (4, 64) -> 1024 waves (1/SIMD),
// throughput from ILP: 25 independent f64 FMA chains + 8-deep feat prefetch.
__global__ __launch_bounds__(256) void k_main(const float* __restrict__ feat,
                                              const double* __restrict__ wpad_g,
                                              const double* __restrict__ b64,
                                              float* __restrict__ boxes_out,
                                              float* __restrict__ scores_out,
                                              float* __restrict__ cls_out)
{
    __shared__ __align__(16) double ldsw[512 * WROW];   // 106496 B
    const int b   = blockIdx.y;
    const int tid = threadIdx.x;

    // stage f64 weights into LDS (coalesced double2)
    {
        const double2* __restrict__ src = (const double2*)wpad_g;
        double2* dst = (double2*)ldsw;
#pragma unroll 1
        for (int i = tid; i < 512 * WROW / 2; i += 256) dst[i] = src[i];
    }
    __syncthreads();

    const int n = blockIdx.x * 256 + tid;
    const float* __restrict__ fp = feat + (size_t)b * 512 * NPOS + n;

    double acc[NOUT];
#pragma unroll
    for (int o = 0; o < NOUT; ++o) acc[o] = 0.0;

#define CH(V, CC) do {                                                        \
    const double2* __restrict__ wr = (const double2*)(ldsw + (size_t)(CC) * WROW); \
    double v = (double)(V);                                                   \
    _Pragma("unroll")                                                         \
    for (int qq = 0; qq < 12; ++qq) {                                         \
        double2 w2 = wr[qq];                                                  \
        acc[2*qq]   = fma(v, w2.x, acc[2*qq]);                                \
        acc[2*qq+1] = fma(v, w2.y, acc[2*qq+1]);                              \
    }                                                                         \
    acc[24] = fma(v, wr[12].x, acc[24]);                                      \
} while (0)

    // group-of-8 channel loop, one group of feat loads in flight ahead
    float f0 = fp[0 * NPOS], f1 = fp[1 * NPOS], f2 = fp[2 * NPOS], f3 = fp[3 * NPOS];
    float f4 = fp[4 * NPOS], f5 = fp[5 * NPOS], f6 = fp[6 * NPOS], f7 = fp[7 * NPOS];
#pragma unroll 1
    for (int c0 = 0; c0 < 512; c0 += 8) {
        int np_ = (c0 + 8 < 512) ? (c0 + 8) : 0;
        float g0 = fp[(size_t)(np_ + 0) * NPOS], g1 = fp[(size_t)(np_ + 1) * NPOS];
        float g2 = fp[(size_t)(np_ + 2) * NPOS], g3 = fp[(size_t)(np_ + 3) * NPOS];
        float g4 = fp[(size_t)(np_ + 4) * NPOS], g5 = fp[(size_t)(np_ + 5) * NPOS];
        float g6 = fp[(size_t)(np_ + 6) * NPOS], g7 = fp[(size_t)(np_ + 7) * NPOS];
        CH(f0, c0 + 0); CH(f1, c0 + 1); CH(f2, c0 + 2); CH(f3, c0 + 3);
        CH(f4, c0 + 4); CH(f5, c0 + 5); CH(f6, c0 + 6); CH(f7, c0 + 7);
        f0 = g0; f1 = g1; f2 = g2; f3 = g3;
        f4 = g4; f5 = g5; f6 = g6; f7 = g7;
    }
#undef CH

    // ---------------- epilogue (f64) ----------------
    double p[NOUT];
#pragma unroll
    for (int o = 0; o < NOUT; ++o) p[o] = acc[o] + b64[o];

    double conf = 1.0 / (1.0 + exp(-p[0]));
    double m = p[1];
#pragma unroll
    for (int i = 2; i <= NCLS; ++i) m = fmax(m, p[i]);
    double e[NCLS];
    double ssum = 0.0;
#pragma unroll
    for (int i = 0; i < NCLS; ++i) { e[i] = exp(p[1 + i] - m); ssum += e[i]; }
    double best = -1.0; int ci = 0;
#pragma unroll
    for (int i = 0; i < NCLS; ++i) {
        double si = conf * (e[i] / ssum);
        if (si > best) { best = si; ci = i; }
    }

    int gx = n & 31, gy = n >> 5;
    double sx = 1.0 / (1.0 + exp(-p[21]));
    double sy = 1.0 / (1.0 + exp(-p[22]));
    double cx = (sx + (double)gx) * 32.0;
    double cy = (sy + (double)gy) * 32.0;
    double bw = exp(p[23]), bh = exp(p[24]);
    double x1 = (cx - bw * 0.5) * (1.0 / 1024.0);
    double y1 = (cy - bh * 0.5) * (1.0 / 1024.0);
    double x2 = (cx + bw * 0.5) * (1.0 / 1024.0);
    double y2 = (cy + bh * 0.5) * (1.0 / 1024.0);
    x1 = fmin(fmax(x1, 0.0), 1.0); y1 = fmin(fmax(y1, 0.0), 1.0);
    x2 = fmin(fmax(x2, 0.0), 1.0); y2 = fmin(fmax(y2, 0.0), 1.0);

    int gi = b * NPOS + n;
    ((float4*)boxes_out)[gi] = make_float4((float)x1, (float)y1, (float)x2, (float)y2);
    scores_out[gi] = (float)best;
    cls_out[gi]    = (float)ci;
}

// ---------------- kernel 2: per-batch bitonic sort (desc score, stable) -------
__global__ __launch_bounds__(256) void k_sort(const float* __restrict__ scores,
                                              const float* __restrict__ boxes,
                                              const float* __restrict__ cls,
                                              int* __restrict__ order,
                                              float4* __restrict__ sbox,
                                              int* __restrict__ scls,
                                              u64* __restrict__ validW)
{
    __shared__ u64 key[NPOS];
    __shared__ u64 vw[16];
    int b = blockIdx.x, tid = threadIdx.x;

    for (int ppos = tid; ppos < NPOS; ppos += 256) {
        u32 bits = __float_as_uint(scores[b * NPOS + ppos]);
        u32 d = ~(bits | 0x80000000u);   // descending-monotone key (scores >= 0)
        key[ppos] = ((u64)d << 32) | (u32)ppos;
    }
    if (tid < 16) vw[tid] = 0ull;
    __syncthreads();

    for (int k = 2; k <= NPOS; k <<= 1) {
        for (int j = k >> 1; j > 0; j >>= 1) {
            for (int idx = tid; idx < NPOS; idx += 256) {
                int l = idx ^ j;
                if (l > idx) {
                    u64 a = key[idx], c = key[l];
                    bool up = ((idx & k) == 0);
                    if ((a > c) == up) { key[idx] = c; key[l] = a; }
                }
            }
            __syncthreads();
        }
    }

    for (int ppos = tid; ppos < NPOS; ppos += 256) {
        u64 kk = key[ppos];
        int idx = (int)(kk & 0xffffffffu);
        order[b * NPOS + ppos] = idx;
        sbox [b * NPOS + ppos] = ((const float4*)boxes)[b * NPOS + idx];
        scls [b * NPOS + ppos] = (int)cls[b * NPOS + idx];
        u32 sb = (~(u32)(kk >> 32)) & 0x7fffffffu;
        float sc = __uint_as_float(sb);
        if (sc > 0.01f) atomicOr(&vw[ppos >> 6], 1ull << (ppos & 63));
    }
    __syncthreads();
    if (tid < 16) validW[b * 16 + tid] = vw[tid];
}

// ---------------- kernel 3: suppression bitmask build (upper triangle) --------
__global__ __launch_bounds__(256) void k_mask(const float4* __restrict__ sbox,
                                              const int* __restrict__ scls,
                                              u64* __restrict__ masks)
{
    __shared__ float4 boxl[NPOS];
    __shared__ float  arl[NPOS];
    __shared__ int    cll[NPOS];
    int b = blockIdx.y, rb = blockIdx.x, tid = threadIdx.x;

    for (int ppos = tid; ppos < NPOS; ppos += 256) {
        float4 bb = sbox[b * NPOS + ppos];
        boxl[ppos] = bb;
        arl[ppos] = (bb.z - bb.x) * (bb.w - bb.y);
        cll[ppos] = scls[b * NPOS + ppos];
    }
    __syncthreads();

    int i = rb * 64 + (tid >> 2);
    int wbase = tid & 3;
    float4 bi = boxl[i];
    float ai = arl[i];
    int ci_ = cll[i];
    u64* mrow = masks + ((size_t)(b * NPOS + i) << 4);

#pragma unroll
    for (int s = 0; s < 4; ++s) {
        int w = wbase + 4 * s;
        u64 bits = 0ull;
        if (w >= rb) {
            for (int t = 0; t < 64; ++t) {
                int jj = (t + 2 * wbase) & 63;
                int j = w * 64 + jj;
                float4 bj = boxl[j];
                float xx1 = fmaxf(bi.x, bj.x), yy1 = fmaxf(bi.y, bj.y);
                float xx2 = fminf(bi.z, bj.z), yy2 = fminf(bi.w, bj.w);
                float ww = fmaxf(1e-28f, xx2 - xx1);
                float hh = fmaxf(1e-28f, yy2 - yy1);
                float inter = ww * hh;
                float uni = ai + arl[j] - inter;
                bool sup = (cll[j] == ci_) && (uni > 0.0f) &&
                           (inter > 0.5f * uni) && (j > i);
                bits |= ((u64)sup) << jj;
            }
        }
        mrow[w] = bits;
    }
}

// ---------------- kernel 4: sequential suppression scan + scatter keep --------
__global__ __launch_bounds__(64) void k_scan(const u64* __restrict__ validW,
                                             const u64* __restrict__ masks,
                                             const int* __restrict__ order,
                                             float* __restrict__ keep_out)
{
    int b = blockIdx.x, lane = threadIdx.x;
    u64 keep = (lane < 16) ? validW[b * 16 + lane] : 0ull;
    const u64* M = masks + (size_t)b * NPOS * 16;
    int myrow = lane >> 4;
    int myw = lane & 15;

    u64 buf[8];
#pragma unroll
    for (int d = 0; d < 8; ++d)
        buf[d] = M[(d * 4 + myrow) * 16 + myw];

    for (int g0 = 0; g0 < 256; g0 += 8) {
#pragma unroll
        for (int d = 0; d < 8; ++d) {
            int g = g0 + d;
            u64 cur = buf[d];
            int gp = g + 8;
            buf[d] = (gp < 256) ? M[(gp * 4 + myrow) * 16 + myw] : 0ull;
            if (__any(cur != 0ull)) {
#pragma unroll
                for (int r = 0; r < 4; ++r) {
                    int i = g * 4 + r;
                    u64 kw = __shfl(keep, i >> 6);
                    if ((kw >> (i & 63)) & 1ull) {
                        u64 mm = __shfl(cur, r * 16 + myw);
                        if (lane < 16) keep &= ~mm;
                    }
                }
            }
        }
    }

#pragma unroll
    for (int t = 0; t < 16; ++t) {
        int ppos = t * 64 + lane;
        u64 kw = __shfl(keep, t);
        float v = ((kw >> lane) & 1ull) ? 1.0f : 0.0f;
        keep_out[b * NPOS + order[b * NPOS + ppos]] = v;
    }
}

// ------------------------------------------------------------------------------
extern "C" void kernel_launch(void* const* d_in, const int* in_sizes, int n_in,
                              void* d_out, int out_size, void* d_ws, size_t ws_size,
                              hipStream_t stream)
{
    const float* feat = (const float*)d_in[0];
    const float* w    = (const float*)d_in[1];
    const float* bias = (const float*)d_in[2];

    float* out = (float*)d_out;
    float* boxes_out  = out;
    float* scores_out = out + NB * NPOS * 4;
    float* cls_out    = out + NB * NPOS * 5;
    float* keep_out   = out + NB * NPOS * 6;

    char* ws = (char*)d_ws;
    double* wpad  = (double*)(ws + OFF_W64);
    double* b64   = (double*)(ws + OFF_B64);
    int*    order = (int*)   (ws + OFF_ORDER);
    float4* sbox  = (float4*)(ws + OFF_SBOX);
    int*    scls  = (int*)   (ws + OFF_SCLS);
    u64*    validW= (u64*)   (ws + OFF_VALID);
    u64*    masks = (u64*)   (ws + OFF_MASK);

    hipLaunchKernelGGL(k_cvt,  dim3(52),     dim3(256), 0, stream, w, bias, wpad, b64);
    hipLaunchKernelGGL(k_main, dim3(4, 64),  dim3(256), 0, stream, feat, wpad, b64,
                       boxes_out, scores_out, cls_out);
    hipLaunchKernelGGL(k_sort, dim3(64),     dim3(256), 0, stream, scores_out,
                       boxes_out, cls_out, order, sbox, scls, validW);
    hipLaunchKernelGGL(k_mask, dim3(16, 64), dim3(256), 0, stream, sbox, scls, masks);
    hipLaunchKernelGGL(k_scan, dim3(64),     dim3(64),  0, stream, validW, masks,
                       order, keep_out);
}